// Round 6
// baseline (152.351 us; speedup 1.0000x reference)
//
#include <hip/hip_runtime.h>
#include <hip/hip_bf16.h>
#include <math.h>

#define NF 64
#define NC 16
#define MAIN_BLOCKS 256
#define MAIN_WAVES  16                 // 1024 threads, 4 waves/SIMD, 1 block/CU
#define TPW 4                          // 16-sample subtiles per wave (64 samples)

typedef __bf16 bf16x8 __attribute__((ext_vector_type(8)));
typedef float f32x4 __attribute__((ext_vector_type(4)));
typedef unsigned int u32;

// async global->LDS, 16B/lane. LDS dest = wave-uniform base (HW adds lane*16).
__device__ __forceinline__ void stage16(const void* gsrc, void* ldst) {
    __builtin_amdgcn_global_load_lds(
        (const __attribute__((address_space(1))) u32*)gsrc,
        (__attribute__((address_space(3))) u32*)ldst,
        16, 0, 0);
}

// ---------------------------------------------------------------------------
// Kernel 1 v6: ROLLED-code Cholesky + substitution (I-fetch was the wall).
// 16 blocks x 64 threads (single wave -> per-wave in-order LDS, no barriers).
// Crout: column j = dot of two finalized LDS rows (float2, 2 accums) ->
// reads pipeline; one exec-masked column write per step.
// Substitution: lane c owns column c of G; xsT[c][*] holds it row-contiguous
// so the p-loop reads its OWN float2 row + broadcast L row. ~3 KB code.
// Stride 66 (264 B): 8-aligned for float2, 2-way bank aliasing (free).
// g stored with chunk-XOR swizzle (jb ^ (row&7)) for gmm_main.
// ---------------------------------------------------------------------------
__global__ __launch_bounds__(64) void gmm_precompute(
    const float* __restrict__ cov,
    const float* __restrict__ means,
    const float* __restrict__ weights,
    __hip_bfloat16* __restrict__ g,
    float* __restrict__ t,
    float* __restrict__ Cc)
{
    const int k = blockIdx.x;
    const int c = threadIdx.x;   // 0..63

    __shared__ __align__(16) float Lm[NF][66];
    __shared__ __align__(16) float xsT[NF][66];

    // coalesced cov load (float2 stores: rows are 8-aligned, not 16)
    {
        const float* src = cov + (long)k * NF * NF;
        #pragma unroll 1
        for (int it = 0; it < 16; ++it) {
            int flat = it * 256 + c * 4;
            float4 v = *(const float4*)(src + flat);
            int r = flat >> 6, ci = flat & 63;
            *(float2*)&Lm[r][ci]     = make_float2(v.x, v.y);
            *(float2*)&Lm[r][ci + 2] = make_float2(v.z, v.w);
        }
    }
    // single-wave block: LDS ops in program order, no barrier needed

    // ---- Crout Cholesky, rolled ----
    float logdiag = 0.0f;
    #pragma unroll 1
    for (int j = 0; j < NF; ++j) {
        float s0 = 0.0f, s1 = 0.0f;
        const float2* rt = (const float2*)&Lm[c][0];
        const float2* rj = (const float2*)&Lm[j][0];
        const int ph = j >> 1;
        #pragma unroll 1
        for (int q = 0; q < ph; ++q) {
            float2 a2 = rt[q], b2 = rj[q];
            s0 = fmaf(a2.x, b2.x, s0);
            s1 = fmaf(a2.y, b2.y, s1);
        }
        float s = Lm[c][j] - (s0 + s1);
        if (j & 1) s = fmaf(-Lm[c][j - 1], Lm[j][j - 1], s);
        float piv = __shfl(s, j);               // pivot from lane j
        float dj  = sqrtf(piv);
        logdiag += 0.5f * __logf(piv);          // uniform
        float rdj = __builtin_amdgcn_rcpf(dj);  // ~1ulp, fine (bf16 downstream)
        float lij = (c == j) ? dj : s * rdj;
        if (c >= j) Lm[c][j] = lij;             // masked: upper A preserved
    }

    // ---- forward substitution, rolled: lane c = column c of G = L^{-1} ----
    #pragma unroll 1
    for (int i = 0; i < NF; ++i) {
        float s0 = (i == c) ? 1.0f : 0.0f, s1 = 0.0f;
        const float2* li = (const float2*)&Lm[i][0];    // broadcast row i of L
        const float2* xc = (const float2*)&xsT[c][0];   // own column, contiguous
        const int ph = i >> 1;
        #pragma unroll 1
        for (int q = 0; q < ph; ++q) {
            float2 lv = li[q], xv = xc[q];
            s0 = fmaf(-lv.x, xv.x, s0);
            s1 = fmaf(-lv.y, xv.y, s1);
        }
        if (i & 1) s0 = fmaf(-Lm[i][i - 1], xsT[c][i - 1], s0);
        float rdi = __builtin_amdgcn_rcpf(Lm[i][i]);
        float xi  = (i >= c) ? (s0 + s1) * rdi : 0.0f;
        xsT[c][i] = xi;                          // own-lane write, in-order
    }

    // ---- g row c (G[c][j] = xsT[j][c]), XOR-swizzled bf16x8 chunks ----
    {
        __hip_bfloat16* grow = g + ((long)(k * NF + c)) * NF;
        #pragma unroll 1
        for (int jb = 0; jb < 8; ++jb) {
            bf16x8 v;
            #pragma unroll
            for (int u = 0; u < 8; ++u)
                v[u] = (__bf16)xsT[jb * 8 + u][c];
            *(bf16x8*)(grow + ((jb ^ (c & 7)) * 8)) = v;
        }
    }

    // ---- t[c] = dot(G row c, mu) ----
    {
        const float* mu = means + k * NF;
        float a0 = 0.0f, a1 = 0.0f;
        #pragma unroll 1
        for (int j = 0; j < NF; j += 2) {
            a0 = fmaf(xsT[j][c],     mu[j],     a0);
            a1 = fmaf(xsT[j + 1][c], mu[j + 1], a1);
        }
        t[k * NF + c] = a0 + a1;
    }

    if (c == 0)
        Cc[k] = __logf(weights[k]) - 0.5f * (float)NF * 1.8378770664093453f - logdiag;
}

// ---------------------------------------------------------------------------
// Kernel 2 v6: persistent G-in-LDS, 1024-thread blocks (16 waves = 4/SIMD,
// double v5's TLP at the same 1 block/CU). -t and Cc staged to LDS so the
// acc-init chain never touches L2. Wave w stages comp w (8 stage16). One
// barrier; then per wave: 64-sample tile, 16 comps x {8 swizzled ds_read,
// 1 t ds_read, 32 MFMA, squares, online LSE}, zero barriers.
// ---------------------------------------------------------------------------
__global__ __launch_bounds__(1024, 4) void gmm_main(
    const float* __restrict__ data,
    const char* __restrict__ gsw,         // swizzled bf16 G, [NC][8192 B]
    const float* __restrict__ t,
    const float* __restrict__ Cc,
    float* __restrict__ partials,
    int nTiles, int N, int totalWaves)
{
    __shared__ __align__(16) char gbuf[NC * 8192];   // 128 KiB
    __shared__ __align__(16) float nt_lds[NC * NF];  // negated t
    __shared__ float cc_lds[NC];

    const int tidx = threadIdx.x;
    const int w    = tidx >> 6;
    const int lane = tidx & 63;
    const int l15  = lane & 15;
    const int lg   = lane >> 4;

    // wave w stages component w (8 KB = 8 x 1KB stage16)
    {
        const char* src = gsw + (size_t)w * 8192;
        char* dst = gbuf + (size_t)w * 8192;
        #pragma unroll
        for (int i = 0; i < 8; ++i)
            stage16(src + i * 1024 + lane * 16, dst + i * 1024);
    }

    // -t / Cc -> LDS
    nt_lds[tidx] = -t[tidx];                 // 1024 threads, 1024 floats
    if (tidx < NC) cc_lds[tidx] = Cc[tidx];

    const int gid = blockIdx.x * MAIN_WAVES + w;

    // swizzled LDS byte offsets (static per lane)
    int offA[4], offB[4];
    #pragma unroll
    for (int rc = 0; rc < 4; ++rc) {
        int row = rc * 16 + l15;
        offA[rc] = row * 128 + ((lg       ^ (l15 & 7)) * 16);
        offB[rc] = row * 128 + (((lg + 4) ^ (l15 & 7)) * 16);
    }

    // first tile's x fragments (overlaps the staging flight)
    bf16x8 xf[TPW][2];
    if (gid < nTiles) {
        const long base = (long)gid * (TPW * 16);
        #pragma unroll
        for (int st = 0; st < TPW; ++st) {
            long row = base + st * 16 + l15;
            if (row > (long)N - 1) row = (long)N - 1;
            const float* xp = data + row * NF + lg * 8;
            float4 a0 = *(const float4*)(xp);
            float4 a1 = *(const float4*)(xp + 4);
            float4 b0 = *(const float4*)(xp + 32);
            float4 b1 = *(const float4*)(xp + 36);
            bf16x8 f0, f1;
            f0[0] = (__bf16)a0.x; f0[1] = (__bf16)a0.y;
            f0[2] = (__bf16)a0.z; f0[3] = (__bf16)a0.w;
            f0[4] = (__bf16)a1.x; f0[5] = (__bf16)a1.y;
            f0[6] = (__bf16)a1.z; f0[7] = (__bf16)a1.w;
            f1[0] = (__bf16)b0.x; f1[1] = (__bf16)b0.y;
            f1[2] = (__bf16)b0.z; f1[3] = (__bf16)b0.w;
            f1[4] = (__bf16)b1.x; f1[5] = (__bf16)b1.y;
            f1[6] = (__bf16)b1.z; f1[7] = (__bf16)b1.w;
            xf[st][0] = f0;
            xf[st][1] = f1;
        }
    }

    __syncthreads();   // G + t staged; only barrier in the kernel

    float wavePartial = 0.0f;

    #pragma unroll 1
    for (int tile = gid; tile < nTiles; tile += totalWaves) {
        const long base = (long)tile * (TPW * 16);
        if (tile != gid) {     // grid-stride continuation (cold path)
            #pragma unroll
            for (int st = 0; st < TPW; ++st) {
                long row = base + st * 16 + l15;
                if (row > (long)N - 1) row = (long)N - 1;
                const float* xp = data + row * NF + lg * 8;
                float4 a0 = *(const float4*)(xp);
                float4 a1 = *(const float4*)(xp + 4);
                float4 b0 = *(const float4*)(xp + 32);
                float4 b1 = *(const float4*)(xp + 36);
                bf16x8 f0, f1;
                f0[0] = (__bf16)a0.x; f0[1] = (__bf16)a0.y;
                f0[2] = (__bf16)a0.z; f0[3] = (__bf16)a0.w;
                f0[4] = (__bf16)a1.x; f0[5] = (__bf16)a1.y;
                f0[6] = (__bf16)a1.z; f0[7] = (__bf16)a1.w;
                f1[0] = (__bf16)b0.x; f1[1] = (__bf16)b0.y;
                f1[2] = (__bf16)b0.z; f1[3] = (__bf16)b0.w;
                f1[4] = (__bf16)b1.x; f1[5] = (__bf16)b1.y;
                f1[6] = (__bf16)b1.z; f1[7] = (__bf16)b1.w;
                xf[st][0] = f0;
                xf[st][1] = f1;
            }
        }

        float m[TPW], s[TPW];
        #pragma unroll
        for (int st = 0; st < TPW; ++st) { m[st] = -INFINITY; s[st] = 0.0f; }

        #pragma unroll 2
        for (int kk = 0; kk < NC; ++kk) {
            float mah[TPW];
            #pragma unroll
            for (int st = 0; st < TPW; ++st) mah[st] = 0.0f;

            #pragma unroll
            for (int rc = 0; rc < 4; ++rc) {
                bf16x8 ga = *(const bf16x8*)(gbuf + kk * 8192 + offA[rc]);
                bf16x8 gb = *(const bf16x8*)(gbuf + kk * 8192 + offB[rc]);
                f32x4 ntv = *(const f32x4*)(&nt_lds[kk * NF + rc * 16 + lg * 4]);
                #pragma unroll
                for (int st = 0; st < TPW; ++st) {
                    f32x4 acc = ntv;
                    acc = __builtin_amdgcn_mfma_f32_16x16x32_bf16(ga, xf[st][0], acc, 0, 0, 0);
                    acc = __builtin_amdgcn_mfma_f32_16x16x32_bf16(gb, xf[st][1], acc, 0, 0, 0);
                    mah[st] = fmaf(acc[0], acc[0], mah[st]);
                    mah[st] = fmaf(acc[1], acc[1], mah[st]);
                    mah[st] = fmaf(acc[2], acc[2], mah[st]);
                    mah[st] = fmaf(acc[3], acc[3], mah[st]);
                }
            }

            float Ck = cc_lds[kk];
            #pragma unroll
            for (int st = 0; st < TPW; ++st) {
                float v = mah[st];
                v += __shfl_xor(v, 16);
                v += __shfl_xor(v, 32);      // all lanes hold full maha
                float wlp = fmaf(-0.5f, v, Ck);
                float mo = m[st];
                float mn = fmaxf(mo, wlp);
                s[st] = s[st] * __expf(mo - mn) + __expf(wlp - mn);
                m[st] = mn;
            }
        }

        if (lg == 0) {
            #pragma unroll
            for (int st = 0; st < TPW; ++st) {
                long sid = base + st * 16 + l15;
                if (sid < (long)N)
                    wavePartial += m[st] + __logf(s[st]);
            }
        }
    }

    #pragma unroll
    for (int off = 1; off < 64; off <<= 1)
        wavePartial += __shfl_xor(wavePartial, off);
    if (lane == 0)
        partials[gid] = wavePartial;
}

// ---------------------------------------------------------------------------
// Kernel 3: deterministic final reduction over per-wave partials.
// ---------------------------------------------------------------------------
__global__ __launch_bounds__(256) void gmm_reduce(
    const float* __restrict__ partials, int n, float* __restrict__ out)
{
    float s = 0.0f;
    for (int i = threadIdx.x; i < n; i += 256)
        s += partials[i];
    #pragma unroll
    for (int off = 1; off < 64; off <<= 1)
        s += __shfl_xor(s, off);
    __shared__ float sm[4];
    const int wave = threadIdx.x >> 6;
    const int lane = threadIdx.x & 63;
    if (lane == 0) sm[wave] = s;
    __syncthreads();
    if (threadIdx.x == 0)
        out[0] = (sm[0] + sm[1]) + (sm[2] + sm[3]);
}

// ---------------------------------------------------------------------------
extern "C" void kernel_launch(void* const* d_in, const int* in_sizes, int n_in,
                              void* d_out, int out_size, void* d_ws, size_t ws_size,
                              hipStream_t stream)
{
    const float* data    = (const float*)d_in[0];
    const float* weights = (const float*)d_in[1];
    const float* means   = (const float*)d_in[2];
    const float* cov     = (const float*)d_in[3];

    const int N = in_sizes[0] / NF;

    char* ws = (char*)d_ws;
    __hip_bfloat16* g = (__hip_bfloat16*)ws;                    // 131072 B (swizzled)
    float* t          = (float*)(ws + 131072);                  // 4096 B
    float* Cc         = (float*)(ws + 131072 + 4096);           // 64 B
    float* partials   = (float*)(ws + 131072 + 4096 + 64);      // totalWaves * 4 B

    const int nTiles     = (N + TPW * 16 - 1) / (TPW * 16);
    const int totalWaves = MAIN_BLOCKS * MAIN_WAVES;

    gmm_precompute<<<NC, 64, 0, stream>>>(cov, means, weights, g, t, Cc);
    gmm_main<<<MAIN_BLOCKS, 64 * MAIN_WAVES, 0, stream>>>(
        data, (const char*)g, t, Cc, partials, nTiles, N, totalWaves);
    gmm_reduce<<<1, 256, 0, stream>>>(partials, totalWaves, (float*)d_out);
}

// Round 7
// 119.509 us; speedup vs baseline: 1.2748x; 1.2748x over previous
//
#include <hip/hip_runtime.h>
#include <hip/hip_bf16.h>
#include <math.h>

#define NF 64
#define NC 16
#define MAIN_BLOCKS 256
#define MAIN_WAVES  16                 // 1024 threads, 4 waves/SIMD, 1 block/CU
#define TPW 4                          // 16-sample subtiles per wave (64 samples)

typedef __bf16 bf16x8 __attribute__((ext_vector_type(8)));
typedef float f32x4 __attribute__((ext_vector_type(4)));
typedef unsigned int u32;

// async global->LDS, 16B/lane. LDS dest = wave-uniform base (HW adds lane*16).
__device__ __forceinline__ void stage16(const void* gsrc, void* ldst) {
    __builtin_amdgcn_global_load_lds(
        (const __attribute__((address_space(1))) u32*)gsrc,
        (__attribute__((address_space(3))) u32*)ldst,
        16, 0, 0);
}

// ---------------------------------------------------------------------------
// Kernel 1 v7: v4's register rank-1 Cholesky + readlane substitution
// (best measured structure), wave-packed: 2 blocks x 8 waves, one component
// per wave, 2 waves/SIMD so pivot-latency and I-stream are shared/hidden.
// No __syncthreads anywhere: per-wave DS ops are in-order (v6-established).
// Per step j (fully unrolled, static indices):
//   wb[c] = a[j]          (publish row j == col j by symmetry; own slot)
//   d = wb[j]             (broadcast; in-order after the write)
//   l[j] = a[j]/sqrt(d);  a[i] -= wb[i] * (a[j]/d)  via float4 broadcasts
//   (full-quad updates may touch dead a[i<=j] -- harmless, bounded garbage)
// Substitution: lane c owns column c of G = L^{-1}; L[i][p] = readlane(l[p],i)
// -- pure VALU chain, zero LDS.
// g stored with chunk-XOR swizzle (jb ^ (row&7)) for gmm_main's conflict-free
// ds_read after linear global_load_lds.
// ---------------------------------------------------------------------------
__global__ __launch_bounds__(512, 2) void gmm_precompute(
    const float* __restrict__ cov,
    const float* __restrict__ means,
    const float* __restrict__ weights,
    __hip_bfloat16* __restrict__ g,
    float* __restrict__ t,
    float* __restrict__ Cc)
{
    const int w = threadIdx.x >> 6;        // wave 0..7
    const int c = threadIdx.x & 63;        // lane owns column c
    const int k = blockIdx.x * 8 + w;      // component

    __shared__ __align__(16) float wbuf[8][68];     // per-wave bcast row (16B-aligned)
    __shared__ float Xs[8][NF][NF + 1];             // per-wave transpose buffer

    float* wb = &wbuf[w][0];

    // column c of cov into regs (lane-consecutive per i -> coalesced)
    float a[NF];
    {
        const float* src = cov + (long)k * NF * NF + c;
        #pragma unroll
        for (int i = 0; i < NF; ++i)
            a[i] = src[i * NF];
    }

    float l[NF];
    float logdiag = 0.0f;

    #pragma unroll
    for (int j = 0; j < NF; ++j) {
        wb[c] = a[j];                     // ds_write own slot
        float d = wb[j];                  // broadcast read; in-order after write
        float sq = sqrtf(d);
        float rd = 1.0f / d;
        logdiag += 0.5f * __logf(d);      // uniform across lanes
        float beta = a[j] * rd;
        l[j] = beta * sq;                 // = a[j]/sqrt(d) = L[c][j]
        if (j + 1 < NF) {
            // float4 broadcast reads of row j; full quads (dead lanes harmless)
            #pragma unroll
            for (int i0 = (j + 1) & ~3; i0 < NF; i0 += 4) {
                float4 v = *(const float4*)(wb + i0);
                a[i0]     = fmaf(-v.x, beta, a[i0]);
                a[i0 + 1] = fmaf(-v.y, beta, a[i0 + 1]);
                a[i0 + 2] = fmaf(-v.z, beta, a[i0 + 2]);
                a[i0 + 3] = fmaf(-v.w, beta, a[i0 + 3]);
            }
        }
    }

    // forward substitution: lane c = column c of G = L^{-1}; readlane chain
    float x[NF];
    #pragma unroll
    for (int i = 0; i < NF; ++i) {
        float s0 = (i == c) ? 1.0f : 0.0f;
        float s1 = 0.0f;
        #pragma unroll
        for (int p = 0; p + 1 < i; p += 2) {
            s0 = fmaf(-__shfl(l[p],     i), x[p],     s0);
            s1 = fmaf(-__shfl(l[p + 1], i), x[p + 1], s1);
        }
        if (i & 1)
            s0 = fmaf(-__shfl(l[i - 1], i), x[i - 1], s0);
        float rdi = 1.0f / __shfl(l[i], i);
        x[i] = (i >= c) ? (s0 + s1) * rdi : 0.0f;
    }

    // transpose through per-wave LDS (same-wave write->read, in-order)
    #pragma unroll
    for (int i = 0; i < NF; ++i) Xs[w][i][c] = x[i];

    // g row c, bf16x8 chunks at XOR-swizzled chunk positions (jb ^ (row&7))
    {
        __hip_bfloat16* grow = g + ((long)(k * NF + c)) * NF;
        #pragma unroll
        for (int jb = 0; jb < 8; ++jb) {
            bf16x8 v;
            #pragma unroll
            for (int u = 0; u < 8; ++u)
                v[u] = (__bf16)Xs[w][c][jb * 8 + u];
            *(bf16x8*)(grow + ((jb ^ (c & 7)) * 8)) = v;
        }
    }

    // t[c] = dot(G row c, mu)
    {
        const float* mu = means + k * NF;
        float a0 = 0.0f, a1 = 0.0f;
        #pragma unroll
        for (int j = 0; j < NF; j += 2) {
            a0 = fmaf(Xs[w][c][j],     mu[j],     a0);
            a1 = fmaf(Xs[w][c][j + 1], mu[j + 1], a1);
        }
        t[k * NF + c] = a0 + a1;
    }

    if (c == 0)
        Cc[k] = __logf(weights[k]) - 0.5f * (float)NF * 1.8378770664093453f - logdiag;
}

// ---------------------------------------------------------------------------
// Kernel 2 v6 (unchanged): persistent G-in-LDS, 1024-thread blocks (16 waves
// = 4/SIMD). -t and Cc staged to LDS. Wave w stages comp w. One barrier;
// then per wave: 64-sample tile, 16 comps x {8 swizzled ds_read, 1 t ds_read,
// 32 MFMA, squares, online LSE}, zero barriers.
// ---------------------------------------------------------------------------
__global__ __launch_bounds__(1024, 4) void gmm_main(
    const float* __restrict__ data,
    const char* __restrict__ gsw,         // swizzled bf16 G, [NC][8192 B]
    const float* __restrict__ t,
    const float* __restrict__ Cc,
    float* __restrict__ partials,
    int nTiles, int N, int totalWaves)
{
    __shared__ __align__(16) char gbuf[NC * 8192];   // 128 KiB
    __shared__ __align__(16) float nt_lds[NC * NF];  // negated t
    __shared__ float cc_lds[NC];

    const int tidx = threadIdx.x;
    const int w    = tidx >> 6;
    const int lane = tidx & 63;
    const int l15  = lane & 15;
    const int lg   = lane >> 4;

    // wave w stages component w (8 KB = 8 x 1KB stage16)
    {
        const char* src = gsw + (size_t)w * 8192;
        char* dst = gbuf + (size_t)w * 8192;
        #pragma unroll
        for (int i = 0; i < 8; ++i)
            stage16(src + i * 1024 + lane * 16, dst + i * 1024);
    }

    // -t / Cc -> LDS
    nt_lds[tidx] = -t[tidx];                 // 1024 threads, 1024 floats
    if (tidx < NC) cc_lds[tidx] = Cc[tidx];

    const int gid = blockIdx.x * MAIN_WAVES + w;

    // swizzled LDS byte offsets (static per lane)
    int offA[4], offB[4];
    #pragma unroll
    for (int rc = 0; rc < 4; ++rc) {
        int row = rc * 16 + l15;
        offA[rc] = row * 128 + ((lg       ^ (l15 & 7)) * 16);
        offB[rc] = row * 128 + (((lg + 4) ^ (l15 & 7)) * 16);
    }

    // first tile's x fragments (overlaps the staging flight)
    bf16x8 xf[TPW][2];
    if (gid < nTiles) {
        const long base = (long)gid * (TPW * 16);
        #pragma unroll
        for (int st = 0; st < TPW; ++st) {
            long row = base + st * 16 + l15;
            if (row > (long)N - 1) row = (long)N - 1;
            const float* xp = data + row * NF + lg * 8;
            float4 a0 = *(const float4*)(xp);
            float4 a1 = *(const float4*)(xp + 4);
            float4 b0 = *(const float4*)(xp + 32);
            float4 b1 = *(const float4*)(xp + 36);
            bf16x8 f0, f1;
            f0[0] = (__bf16)a0.x; f0[1] = (__bf16)a0.y;
            f0[2] = (__bf16)a0.z; f0[3] = (__bf16)a0.w;
            f0[4] = (__bf16)a1.x; f0[5] = (__bf16)a1.y;
            f0[6] = (__bf16)a1.z; f0[7] = (__bf16)a1.w;
            f1[0] = (__bf16)b0.x; f1[1] = (__bf16)b0.y;
            f1[2] = (__bf16)b0.z; f1[3] = (__bf16)b0.w;
            f1[4] = (__bf16)b1.x; f1[5] = (__bf16)b1.y;
            f1[6] = (__bf16)b1.z; f1[7] = (__bf16)b1.w;
            xf[st][0] = f0;
            xf[st][1] = f1;
        }
    }

    __syncthreads();   // G + t staged; only barrier in the kernel

    float wavePartial = 0.0f;

    #pragma unroll 1
    for (int tile = gid; tile < nTiles; tile += totalWaves) {
        const long base = (long)tile * (TPW * 16);
        if (tile != gid) {     // grid-stride continuation (cold path)
            #pragma unroll
            for (int st = 0; st < TPW; ++st) {
                long row = base + st * 16 + l15;
                if (row > (long)N - 1) row = (long)N - 1;
                const float* xp = data + row * NF + lg * 8;
                float4 a0 = *(const float4*)(xp);
                float4 a1 = *(const float4*)(xp + 4);
                float4 b0 = *(const float4*)(xp + 32);
                float4 b1 = *(const float4*)(xp + 36);
                bf16x8 f0, f1;
                f0[0] = (__bf16)a0.x; f0[1] = (__bf16)a0.y;
                f0[2] = (__bf16)a0.z; f0[3] = (__bf16)a0.w;
                f0[4] = (__bf16)a1.x; f0[5] = (__bf16)a1.y;
                f0[6] = (__bf16)a1.z; f0[7] = (__bf16)a1.w;
                f1[0] = (__bf16)b0.x; f1[1] = (__bf16)b0.y;
                f1[2] = (__bf16)b0.z; f1[3] = (__bf16)b0.w;
                f1[4] = (__bf16)b1.x; f1[5] = (__bf16)b1.y;
                f1[6] = (__bf16)b1.z; f1[7] = (__bf16)b1.w;
                xf[st][0] = f0;
                xf[st][1] = f1;
            }
        }

        float m[TPW], s[TPW];
        #pragma unroll
        for (int st = 0; st < TPW; ++st) { m[st] = -INFINITY; s[st] = 0.0f; }

        #pragma unroll 2
        for (int kk = 0; kk < NC; ++kk) {
            float mah[TPW];
            #pragma unroll
            for (int st = 0; st < TPW; ++st) mah[st] = 0.0f;

            #pragma unroll
            for (int rc = 0; rc < 4; ++rc) {
                bf16x8 ga = *(const bf16x8*)(gbuf + kk * 8192 + offA[rc]);
                bf16x8 gb = *(const bf16x8*)(gbuf + kk * 8192 + offB[rc]);
                f32x4 ntv = *(const f32x4*)(&nt_lds[kk * NF + rc * 16 + lg * 4]);
                #pragma unroll
                for (int st = 0; st < TPW; ++st) {
                    f32x4 acc = ntv;
                    acc = __builtin_amdgcn_mfma_f32_16x16x32_bf16(ga, xf[st][0], acc, 0, 0, 0);
                    acc = __builtin_amdgcn_mfma_f32_16x16x32_bf16(gb, xf[st][1], acc, 0, 0, 0);
                    mah[st] = fmaf(acc[0], acc[0], mah[st]);
                    mah[st] = fmaf(acc[1], acc[1], mah[st]);
                    mah[st] = fmaf(acc[2], acc[2], mah[st]);
                    mah[st] = fmaf(acc[3], acc[3], mah[st]);
                }
            }

            float Ck = cc_lds[kk];
            #pragma unroll
            for (int st = 0; st < TPW; ++st) {
                float v = mah[st];
                v += __shfl_xor(v, 16);
                v += __shfl_xor(v, 32);      // all lanes hold full maha
                float wlp = fmaf(-0.5f, v, Ck);
                float mo = m[st];
                float mn = fmaxf(mo, wlp);
                s[st] = s[st] * __expf(mo - mn) + __expf(wlp - mn);
                m[st] = mn;
            }
        }

        if (lg == 0) {
            #pragma unroll
            for (int st = 0; st < TPW; ++st) {
                long sid = base + st * 16 + l15;
                if (sid < (long)N)
                    wavePartial += m[st] + __logf(s[st]);
            }
        }
    }

    #pragma unroll
    for (int off = 1; off < 64; off <<= 1)
        wavePartial += __shfl_xor(wavePartial, off);
    if (lane == 0)
        partials[gid] = wavePartial;
}

// ---------------------------------------------------------------------------
// Kernel 3: deterministic final reduction over per-wave partials.
// ---------------------------------------------------------------------------
__global__ __launch_bounds__(256) void gmm_reduce(
    const float* __restrict__ partials, int n, float* __restrict__ out)
{
    float s = 0.0f;
    for (int i = threadIdx.x; i < n; i += 256)
        s += partials[i];
    #pragma unroll
    for (int off = 1; off < 64; off <<= 1)
        s += __shfl_xor(s, off);
    __shared__ float sm[4];
    const int wave = threadIdx.x >> 6;
    const int lane = threadIdx.x & 63;
    if (lane == 0) sm[wave] = s;
    __syncthreads();
    if (threadIdx.x == 0)
        out[0] = (sm[0] + sm[1]) + (sm[2] + sm[3]);
}

// ---------------------------------------------------------------------------
extern "C" void kernel_launch(void* const* d_in, const int* in_sizes, int n_in,
                              void* d_out, int out_size, void* d_ws, size_t ws_size,
                              hipStream_t stream)
{
    const float* data    = (const float*)d_in[0];
    const float* weights = (const float*)d_in[1];
    const float* means   = (const float*)d_in[2];
    const float* cov     = (const float*)d_in[3];

    const int N = in_sizes[0] / NF;

    char* ws = (char*)d_ws;
    __hip_bfloat16* g = (__hip_bfloat16*)ws;                    // 131072 B (swizzled)
    float* t          = (float*)(ws + 131072);                  // 4096 B
    float* Cc         = (float*)(ws + 131072 + 4096);           // 64 B
    float* partials   = (float*)(ws + 131072 + 4096 + 64);      // totalWaves * 4 B

    const int nTiles     = (N + TPW * 16 - 1) / (TPW * 16);
    const int totalWaves = MAIN_BLOCKS * MAIN_WAVES;

    gmm_precompute<<<2, 512, 0, stream>>>(cov, means, weights, g, t, Cc);
    gmm_main<<<MAIN_BLOCKS, 64 * MAIN_WAVES, 0, stream>>>(
        data, (const char*)g, t, Cc, partials, nTiles, N, totalWaves);
    gmm_reduce<<<1, 256, 0, stream>>>(partials, totalWaves, (float*)d_out);
}

// Round 8
// 69.104 us; speedup vs baseline: 2.2046x; 1.7294x over previous
//
#include <hip/hip_runtime.h>
#include <hip/hip_bf16.h>
#include <math.h>

#define NF 64
#define NC 16
#define MAIN_BLOCKS 256
#define MAIN_WAVES  13                 // 832 thr; 256*13=3328 waves vs 3125 tiles
#define TPW 4                          // 16-sample subtiles per wave (64 samples)

typedef __bf16 bf16x8 __attribute__((ext_vector_type(8)));
typedef float f32x4 __attribute__((ext_vector_type(4)));
typedef unsigned int u32;

// async global->LDS, 16B/lane. LDS dest = wave-uniform base (HW adds lane*16).
__device__ __forceinline__ void stage16(const void* gsrc, void* ldst) {
    __builtin_amdgcn_global_load_lds(
        (const __attribute__((address_space(1))) u32*)gsrc,
        (__attribute__((address_space(3))) u32*)ldst,
        16, 0, 0);
}

// ---------------------------------------------------------------------------
// Kernel 1 v8: 4-wave cooperative Cholesky + inverse, ROLLED phase loops.
// 16 blocks (1 component) x 256 threads. Lane (w,c) owns rows [16w,16w+16)
// of column c in 16 registers (all indices static: outer loop rolled over
// 4 phases, inner 16 steps unrolled).
// Cholesky step j (=16q+jj): owner wave q publishes trailing row j
// (wb[c]=a_loc[jj]; row j == col j by symmetry); barrier; every lane:
//   d=wb[j], beta_c=wb[c]/d, LT[j][c]=wb[c]*rsq  (column j of L, own slot),
//   a_loc[r] -= wb[16w+r]*beta_c (float4 broadcast reads; dead rows take
//   harmless garbage updates -> no predication).
// Substitution (right-looking, S=I): step i: owner publishes G row i
// (gv = s_loc[ii]*rsq_loc[ii]); barrier; s_loc[r] -= LT[i][16w+r]*gw[c].
// Code ~13KB -> L1I-resident (the unrolled v4/v7 bodies were ~50KB and
// I-fetch-bound at 37-77us).
// ---------------------------------------------------------------------------
__global__ __launch_bounds__(256) void gmm_precompute(
    const float* __restrict__ cov,
    const float* __restrict__ means,
    const float* __restrict__ weights,
    __hip_bfloat16* __restrict__ g,
    float* __restrict__ t,
    float* __restrict__ Cc)
{
    const int w = threadIdx.x >> 6;   // wave 0..3: rows [16w,16w+16)
    const int c = threadIdx.x & 63;   // lane owns column c
    const int k = blockIdx.x;

    __shared__ __align__(16) float LT[NF][68];   // LT[j][r] = L[r][j]
    __shared__ float Xs[NF][65];                 // Xs[i][c] = G[i][c]
    __shared__ __align__(16) float wb2[2][68];   // ping-pong published row
    __shared__ __align__(16) float gw2[2][68];   // ping-pong published G row

    // a_loc[r] = A[16w+r][c]; per-r the 64 lanes read 64 consecutive floats
    float a_loc[16];
    {
        const float* src = cov + (long)k * NF * NF + (w * 16) * NF + c;
        #pragma unroll
        for (int r = 0; r < 16; ++r)
            a_loc[r] = src[r * NF];
    }

    float rsq_loc[16];          // 1/L[j][j] for my owned steps
    float logdiag = 0.0f;

    // ---- Cholesky: 4 rolled phases x 16 unrolled steps ----
    #pragma unroll 1
    for (int q = 0; q < 4; ++q) {
        #pragma unroll
        for (int jj = 0; jj < 16; ++jj) {
            float* wb = wb2[jj & 1];
            if (w == q) wb[c] = a_loc[jj];       // publish trailing row j
            __syncthreads();
            const int j = q * 16 + jj;
            float ajc = wb[c];                   // A[j][c] (own slot)
            float d   = wb[j];                   // pivot (broadcast)
            float sq  = sqrtf(d);
            float rsq = __builtin_amdgcn_rcpf(sq);
            float rd  = __builtin_amdgcn_rcpf(d);
            logdiag += 0.5f * __logf(d);         // uniform across lanes
            if (w == q) rsq_loc[jj] = rsq;
            LT[j][c] = ajc * rsq;                // column j of L (own slot)
            float beta = ajc * rd;
            const float4* wv = (const float4*)(wb + w * 16);
            #pragma unroll
            for (int rr = 0; rr < 16; rr += 4) {
                float4 v = wv[rr >> 2];          // broadcast: rows 16w+rr..
                a_loc[rr]     = fmaf(-v.x, beta, a_loc[rr]);
                a_loc[rr + 1] = fmaf(-v.y, beta, a_loc[rr + 1]);
                a_loc[rr + 2] = fmaf(-v.z, beta, a_loc[rr + 2]);
                a_loc[rr + 3] = fmaf(-v.w, beta, a_loc[rr + 3]);
            }
        }
    }

    // ---- substitution: S = I; G row i published at step i ----
    float s_loc[16];
    #pragma unroll
    for (int r = 0; r < 16; ++r)
        s_loc[r] = (w * 16 + r == c) ? 1.0f : 0.0f;

    #pragma unroll 1
    for (int q = 0; q < 4; ++q) {
        #pragma unroll
        for (int ii = 0; ii < 16; ++ii) {
            const int i = q * 16 + ii;
            float* gw = gw2[ii & 1];
            if (w == q) {
                float gv = s_loc[ii] * rsq_loc[ii];
                gw[c] = gv;                      // publish G[i][c]
                Xs[i][c] = gv;                   // collect output
            }
            __syncthreads();
            float gc = gw[c];                    // G[i][c] (own slot)
            const float4* lv4 = (const float4*)(&LT[i][w * 16]);
            #pragma unroll
            for (int rr = 0; rr < 16; rr += 4) {
                float4 v = lv4[rr >> 2];         // L[16w+rr..][i] broadcast
                s_loc[rr]     = fmaf(-v.x, gc, s_loc[rr]);
                s_loc[rr + 1] = fmaf(-v.y, gc, s_loc[rr + 1]);
                s_loc[rr + 2] = fmaf(-v.z, gc, s_loc[rr + 2]);
                s_loc[rr + 3] = fmaf(-v.w, gc, s_loc[rr + 3]);
            }
        }
    }
    __syncthreads();

    // ---- g row c (lane c), wave w writes chunks jb=2w,2w+1, XOR-swizzled ----
    {
        __hip_bfloat16* grow = g + ((long)(k * NF + c)) * NF;
        #pragma unroll
        for (int h = 0; h < 2; ++h) {
            int jb = w * 2 + h;
            bf16x8 v;
            #pragma unroll
            for (int u = 0; u < 8; ++u)
                v[u] = (__bf16)Xs[c][jb * 8 + u];   // G[c][j]; stride-65 rows
            *(bf16x8*)(grow + ((jb ^ (c & 7)) * 8)) = v;
        }
    }

    // ---- t[c] = dot(G row c, mu); Cc ----
    if (w == 0) {
        const float* mu = means + k * NF;
        float a0 = 0.0f, a1 = 0.0f;
        #pragma unroll
        for (int j = 0; j < NF; j += 2) {
            a0 = fmaf(Xs[c][j],     mu[j],     a0);
            a1 = fmaf(Xs[c][j + 1], mu[j + 1], a1);
        }
        t[k * NF + c] = a0 + a1;
        if (c == 0)
            Cc[k] = __logf(weights[k]) - 0.5f * (float)NF * 1.8378770664093453f - logdiag;
    }
}

// ---------------------------------------------------------------------------
// Kernel 2 v8: persistent G-in-LDS; 13 waves/block (832 thr) so 3328 waves
// cover 3125 tiles at 94% balance across ALL 256 CUs (16-wave blocks left
// 60 CUs idle). Otherwise identical to v6: stage all 16 comps (128 KiB,
// pre-swizzled) once, -t/Cc in LDS, one barrier, zero steady-state barriers.
// ---------------------------------------------------------------------------
__global__ __launch_bounds__(832, 4) void gmm_main(
    const float* __restrict__ data,
    const char* __restrict__ gsw,         // swizzled bf16 G, [NC][8192 B]
    const float* __restrict__ t,
    const float* __restrict__ Cc,
    float* __restrict__ partials,
    int nTiles, int N, int totalWaves)
{
    __shared__ __align__(16) char gbuf[NC * 8192];   // 128 KiB
    __shared__ __align__(16) float nt_lds[NC * NF];  // negated t
    __shared__ float cc_lds[NC];

    const int tidx = threadIdx.x;
    const int w    = tidx >> 6;
    const int lane = tidx & 63;
    const int l15  = lane & 15;
    const int lg   = lane >> 4;

    // stage G: wave w covers comps {w, w+13} (<16)
    for (int i = w; i < NC; i += MAIN_WAVES) {
        const char* src = gsw + (size_t)i * 8192;
        char* dst = gbuf + (size_t)i * 8192;
        #pragma unroll
        for (int u = 0; u < 8; ++u)
            stage16(src + u * 1024 + lane * 16, dst + u * 1024);
    }

    // -t / Cc -> LDS
    for (int i = tidx; i < NC * NF; i += 832) nt_lds[i] = -t[i];
    if (tidx < NC) cc_lds[tidx] = Cc[tidx];

    const int gid = blockIdx.x * MAIN_WAVES + w;

    // swizzled LDS byte offsets (static per lane)
    int offA[4], offB[4];
    #pragma unroll
    for (int rc = 0; rc < 4; ++rc) {
        int row = rc * 16 + l15;
        offA[rc] = row * 128 + ((lg       ^ (l15 & 7)) * 16);
        offB[rc] = row * 128 + (((lg + 4) ^ (l15 & 7)) * 16);
    }

    // first tile's x fragments (overlaps staging flight)
    bf16x8 xf[TPW][2];
    if (gid < nTiles) {
        const long base = (long)gid * (TPW * 16);
        #pragma unroll
        for (int st = 0; st < TPW; ++st) {
            long row = base + st * 16 + l15;
            if (row > (long)N - 1) row = (long)N - 1;
            const float* xp = data + row * NF + lg * 8;
            float4 a0 = *(const float4*)(xp);
            float4 a1 = *(const float4*)(xp + 4);
            float4 b0 = *(const float4*)(xp + 32);
            float4 b1 = *(const float4*)(xp + 36);
            bf16x8 f0, f1;
            f0[0] = (__bf16)a0.x; f0[1] = (__bf16)a0.y;
            f0[2] = (__bf16)a0.z; f0[3] = (__bf16)a0.w;
            f0[4] = (__bf16)a1.x; f0[5] = (__bf16)a1.y;
            f0[6] = (__bf16)a1.z; f0[7] = (__bf16)a1.w;
            f1[0] = (__bf16)b0.x; f1[1] = (__bf16)b0.y;
            f1[2] = (__bf16)b0.z; f1[3] = (__bf16)b0.w;
            f1[4] = (__bf16)b1.x; f1[5] = (__bf16)b1.y;
            f1[6] = (__bf16)b1.z; f1[7] = (__bf16)b1.w;
            xf[st][0] = f0;
            xf[st][1] = f1;
        }
    }

    __syncthreads();   // G + t staged; only barrier in the kernel

    float wavePartial = 0.0f;

    #pragma unroll 1
    for (int tile = gid; tile < nTiles; tile += totalWaves) {
        const long base = (long)tile * (TPW * 16);
        if (tile != gid) {     // grid-stride continuation (cold path)
            #pragma unroll
            for (int st = 0; st < TPW; ++st) {
                long row = base + st * 16 + l15;
                if (row > (long)N - 1) row = (long)N - 1;
                const float* xp = data + row * NF + lg * 8;
                float4 a0 = *(const float4*)(xp);
                float4 a1 = *(const float4*)(xp + 4);
                float4 b0 = *(const float4*)(xp + 32);
                float4 b1 = *(const float4*)(xp + 36);
                bf16x8 f0, f1;
                f0[0] = (__bf16)a0.x; f0[1] = (__bf16)a0.y;
                f0[2] = (__bf16)a0.z; f0[3] = (__bf16)a0.w;
                f0[4] = (__bf16)a1.x; f0[5] = (__bf16)a1.y;
                f0[6] = (__bf16)a1.z; f0[7] = (__bf16)a1.w;
                f1[0] = (__bf16)b0.x; f1[1] = (__bf16)b0.y;
                f1[2] = (__bf16)b0.z; f1[3] = (__bf16)b0.w;
                f1[4] = (__bf16)b1.x; f1[5] = (__bf16)b1.y;
                f1[6] = (__bf16)b1.z; f1[7] = (__bf16)b1.w;
                xf[st][0] = f0;
                xf[st][1] = f1;
            }
        }

        float m[TPW], s[TPW];
        #pragma unroll
        for (int st = 0; st < TPW; ++st) { m[st] = -INFINITY; s[st] = 0.0f; }

        #pragma unroll 2
        for (int kk = 0; kk < NC; ++kk) {
            float mah[TPW];
            #pragma unroll
            for (int st = 0; st < TPW; ++st) mah[st] = 0.0f;

            #pragma unroll
            for (int rc = 0; rc < 4; ++rc) {
                bf16x8 ga = *(const bf16x8*)(gbuf + kk * 8192 + offA[rc]);
                bf16x8 gb = *(const bf16x8*)(gbuf + kk * 8192 + offB[rc]);
                f32x4 ntv = *(const f32x4*)(&nt_lds[kk * NF + rc * 16 + lg * 4]);
                #pragma unroll
                for (int st = 0; st < TPW; ++st) {
                    f32x4 acc = ntv;
                    acc = __builtin_amdgcn_mfma_f32_16x16x32_bf16(ga, xf[st][0], acc, 0, 0, 0);
                    acc = __builtin_amdgcn_mfma_f32_16x16x32_bf16(gb, xf[st][1], acc, 0, 0, 0);
                    mah[st] = fmaf(acc[0], acc[0], mah[st]);
                    mah[st] = fmaf(acc[1], acc[1], mah[st]);
                    mah[st] = fmaf(acc[2], acc[2], mah[st]);
                    mah[st] = fmaf(acc[3], acc[3], mah[st]);
                }
            }

            float Ck = cc_lds[kk];
            #pragma unroll
            for (int st = 0; st < TPW; ++st) {
                float v = mah[st];
                v += __shfl_xor(v, 16);
                v += __shfl_xor(v, 32);      // all lanes hold full maha
                float wlp = fmaf(-0.5f, v, Ck);
                float mo = m[st];
                float mn = fmaxf(mo, wlp);
                s[st] = s[st] * __expf(mo - mn) + __expf(wlp - mn);
                m[st] = mn;
            }
        }

        if (lg == 0) {
            #pragma unroll
            for (int st = 0; st < TPW; ++st) {
                long sid = base + st * 16 + l15;
                if (sid < (long)N)
                    wavePartial += m[st] + __logf(s[st]);
            }
        }
    }

    #pragma unroll
    for (int off = 1; off < 64; off <<= 1)
        wavePartial += __shfl_xor(wavePartial, off);
    if (lane == 0)
        partials[gid] = wavePartial;
}

// ---------------------------------------------------------------------------
// Kernel 3: deterministic final reduction over per-wave partials.
// ---------------------------------------------------------------------------
__global__ __launch_bounds__(256) void gmm_reduce(
    const float* __restrict__ partials, int n, float* __restrict__ out)
{
    float s = 0.0f;
    for (int i = threadIdx.x; i < n; i += 256)
        s += partials[i];
    #pragma unroll
    for (int off = 1; off < 64; off <<= 1)
        s += __shfl_xor(s, off);
    __shared__ float sm[4];
    const int wave = threadIdx.x >> 6;
    const int lane = threadIdx.x & 63;
    if (lane == 0) sm[wave] = s;
    __syncthreads();
    if (threadIdx.x == 0)
        out[0] = (sm[0] + sm[1]) + (sm[2] + sm[3]);
}

// ---------------------------------------------------------------------------
extern "C" void kernel_launch(void* const* d_in, const int* in_sizes, int n_in,
                              void* d_out, int out_size, void* d_ws, size_t ws_size,
                              hipStream_t stream)
{
    const float* data    = (const float*)d_in[0];
    const float* weights = (const float*)d_in[1];
    const float* means   = (const float*)d_in[2];
    const float* cov     = (const float*)d_in[3];

    const int N = in_sizes[0] / NF;

    char* ws = (char*)d_ws;
    __hip_bfloat16* g = (__hip_bfloat16*)ws;                    // 131072 B (swizzled)
    float* t          = (float*)(ws + 131072);                  // 4096 B
    float* Cc         = (float*)(ws + 131072 + 4096);           // 64 B
    float* partials   = (float*)(ws + 131072 + 4096 + 64);      // totalWaves * 4 B

    const int nTiles     = (N + TPW * 16 - 1) / (TPW * 16);
    const int totalWaves = MAIN_BLOCKS * MAIN_WAVES;

    gmm_precompute<<<NC, 256, 0, stream>>>(cov, means, weights, g, t, Cc);
    gmm_main<<<MAIN_BLOCKS, 64 * MAIN_WAVES, 0, stream>>>(
        data, (const char*)g, t, Cc, partials, nTiles, N, totalWaves);
    gmm_reduce<<<1, 256, 0, stream>>>(partials, totalWaves, (float*)d_out);
}